// Round 1
// baseline (526.163 us; speedup 1.0000x reference)
//
#include <hip/hip_runtime.h>

// ---------------------------------------------------------------------------
// LinearAttention (FAVOR-style):
//   q' = exp(x @ Wq); k' = exp(x @ Wk)
//   kv[b] = k'[b]^T @ x[b];  num = q' @ kv;  out = num / (rowsum(q') + 1e-8)
// All matmuls via bf16 MFMA 16x16x32 (fp32 accumulate).
// ---------------------------------------------------------------------------

#define EMBED 1024
#define PROJ  256
#define LSEQ  4096
#define BATCH 8
#define MTOT  (BATCH * LSEQ)  // 32768

typedef short  bfrag __attribute__((ext_vector_type(8)));  // 8 bf16 for MFMA a/b
typedef float  f4    __attribute__((ext_vector_type(4)));  // MFMA c/d
typedef unsigned short u16x8 __attribute__((ext_vector_type(8)));
typedef unsigned short u16x4 __attribute__((ext_vector_type(4)));

static __device__ __forceinline__ unsigned short f2bf(float f) {
  unsigned int u = __builtin_bit_cast(unsigned int, f);
  u += 0x7fffu + ((u >> 16) & 1u);  // round-to-nearest-even
  return (unsigned short)(u >> 16);
}
static __device__ __forceinline__ float bf2f(unsigned short h) {
  unsigned int u = ((unsigned int)h) << 16;
  return __builtin_bit_cast(float, u);
}

// ---------------------------------------------------------------------------
// Stage A: C[m, n] = exp( x[m, :] @ W[:, n] ), W = concat(Wq, Wk) cols.
// M=32768, N=512, K=1024. Block tile 128x64, BK=32. 4 waves as 2x2, wave=64x32.
// q-half written [m][e] row-major (qp). k-half written TRANSPOSED into
// kT[b][e][l] via LDS rearrange (so the kv GEMM's A-loads are coalesced).
// ---------------------------------------------------------------------------
__global__ __launch_bounds__(256) void proj_exp_kernel(
    const float* __restrict__ x, const float* __restrict__ qw,
    const float* __restrict__ kw, unsigned short* __restrict__ qp,
    unsigned short* __restrict__ kT) {
  __shared__ unsigned short Al[128][40];   // A tile [m][k], pad->40
  __shared__ unsigned short Bl[64][40];    // B tile transposed [n][k]
  __shared__ unsigned short Tt[64][136];   // transpose buffer [e][l], pad->136

  const int tid  = threadIdx.x;
  const int wave = tid >> 6, lane = tid & 63;
  const int quad = lane >> 4, l16 = lane & 15;
  const int wm = wave >> 1, wn = wave & 1;

  const int n0 = blockIdx.x * 64;   // 0..511 over [Wq | Wk]
  const int m0 = blockIdx.y * 128;  // 0..32767
  const bool is_q = (n0 < PROJ);
  const float* W = is_q ? (qw + n0) : (kw + (n0 - PROJ));

  f4 acc[4][2];
#pragma unroll
  for (int i = 0; i < 4; i++)
#pragma unroll
    for (int j = 0; j < 2; j++) acc[i][j] = (f4){0.f, 0.f, 0.f, 0.f};

  const int bn = tid & 63, bk = tid >> 6;  // B staging coords

  for (int k0 = 0; k0 < EMBED; k0 += 32) {
    // stage A tile: 128x32 fp32 -> bf16 (coalesced float4 loads)
#pragma unroll
    for (int it = 0; it < 4; it++) {
      int slot = it * 256 + tid;
      int row = slot >> 3, kq = slot & 7;
      const float4 v = *(const float4*)(x + (size_t)(m0 + row) * EMBED + k0 + kq * 4);
      *(u16x4*)&Al[row][kq * 4] =
          (u16x4){f2bf(v.x), f2bf(v.y), f2bf(v.z), f2bf(v.w)};
    }
    // stage B tile transposed: Bl[n][k] = W[k][n] (loads coalesced across n)
    {
      u16x8 h;
#pragma unroll
      for (int i = 0; i < 8; i++)
        h[i] = f2bf(W[(size_t)(k0 + bk * 8 + i) * PROJ + bn]);
      *(u16x8*)&Bl[bn][bk * 8] = h;
    }
    __syncthreads();

    bfrag a[4], b[2];
#pragma unroll
    for (int mt = 0; mt < 4; mt++)
      a[mt] = *(const bfrag*)&Al[wm * 64 + mt * 16 + l16][quad * 8];
#pragma unroll
    for (int nt = 0; nt < 2; nt++)
      b[nt] = *(const bfrag*)&Bl[wn * 32 + nt * 16 + l16][quad * 8];
#pragma unroll
    for (int mt = 0; mt < 4; mt++)
#pragma unroll
      for (int nt = 0; nt < 2; nt++)
        acc[mt][nt] =
            __builtin_amdgcn_mfma_f32_16x16x32_bf16(a[mt], b[nt], acc[mt][nt], 0, 0, 0);
    __syncthreads();
  }

  if (is_q) {
#pragma unroll
    for (int mt = 0; mt < 4; mt++)
#pragma unroll
      for (int nt = 0; nt < 2; nt++)
#pragma unroll
        for (int r = 0; r < 4; r++) {
          int m = m0 + wm * 64 + mt * 16 + quad * 4 + r;
          int e = n0 + wn * 32 + nt * 16 + l16;
          qp[(size_t)m * PROJ + e] = f2bf(__expf(acc[mt][nt][r]));
        }
  } else {
    // write exp() results into LDS as [e][l], then copy out coalesced rows
#pragma unroll
    for (int mt = 0; mt < 4; mt++)
#pragma unroll
      for (int nt = 0; nt < 2; nt++) {
        u16x4 h;
#pragma unroll
        for (int r = 0; r < 4; r++) h[r] = f2bf(__expf(acc[mt][nt][r]));
        *(u16x4*)&Tt[wn * 32 + nt * 16 + l16][wm * 64 + mt * 16 + quad * 4] = h;
      }
    __syncthreads();
    const int bb = m0 >> 12;        // batch
    const int l0 = m0 & 4095;       // seq offset within batch
    const int ebase = n0 - PROJ;
#pragma unroll
    for (int it = 0; it < 4; it++) {
      int slot = it * 256 + tid;
      int e = slot >> 4, ch = slot & 15;
      u16x8 v = *(const u16x8*)&Tt[e][ch * 8];
      *(u16x8*)(kT + (size_t)(bb * PROJ + ebase + e) * LSEQ + l0 + ch * 8) = v;
    }
  }
}

// ---------------------------------------------------------------------------
// zinv[m] = 1 / (sum_e q'[m][e] + 1e-8). One wave per row (256 = 64 lanes x4).
// ---------------------------------------------------------------------------
__global__ __launch_bounds__(256) void zinv_kernel(
    const unsigned short* __restrict__ qp, float* __restrict__ zinv) {
  int m = blockIdx.x * 4 + (threadIdx.x >> 6);
  int lane = threadIdx.x & 63;
  u16x4 h = *(const u16x4*)(qp + (size_t)m * PROJ + lane * 4);
  float s = bf2f(h[0]) + bf2f(h[1]) + bf2f(h[2]) + bf2f(h[3]);
#pragma unroll
  for (int off = 32; off; off >>= 1) s += __shfl_xor(s, off);
  if (lane == 0) zinv[m] = 1.0f / (s + 1e-8f);
}

// ---------------------------------------------------------------------------
// Stage B: kv[b][e][d] = sum_l kT[b][e][l] * x[b][l][d].
// Per batch M=256(e), N=1024(d), K=4096(l). Block 64x64, BK=32, waves 2x2.
// ---------------------------------------------------------------------------
__global__ __launch_bounds__(256) void kv_kernel(
    const unsigned short* __restrict__ kT, const float* __restrict__ x,
    unsigned short* __restrict__ kv) {
  __shared__ unsigned short Al[64][40];  // [e][l]
  __shared__ unsigned short Bl[64][40];  // [d][l] (x transposed)
  const int tid  = threadIdx.x;
  const int wave = tid >> 6, lane = tid & 63;
  const int quad = lane >> 4, l16 = lane & 15;
  const int wm = wave >> 1, wn = wave & 1;
  const int d0 = blockIdx.x * 64;
  const int e0 = blockIdx.y * 64;
  const int b  = blockIdx.z;
  const unsigned short* kTb = kT + (size_t)b * PROJ * LSEQ;
  const float* xb = x + (size_t)b * LSEQ * EMBED;

  f4 acc[2][2];
#pragma unroll
  for (int i = 0; i < 2; i++)
#pragma unroll
    for (int j = 0; j < 2; j++) acc[i][j] = (f4){0.f, 0.f, 0.f, 0.f};

  const int ae = tid >> 2, ac = tid & 3;   // A staging: 64 rows x 4 chunks of 8
  const int bn = tid & 63, bk = tid >> 6;  // B staging

  for (int k0 = 0; k0 < LSEQ; k0 += 32) {
    *(u16x8*)&Al[ae][ac * 8] =
        *(const u16x8*)(kTb + (size_t)(e0 + ae) * LSEQ + k0 + ac * 8);
    u16x8 h;
#pragma unroll
    for (int i = 0; i < 8; i++)
      h[i] = f2bf(xb[(size_t)(k0 + bk * 8 + i) * EMBED + d0 + bn]);
    *(u16x8*)&Bl[bn][bk * 8] = h;
    __syncthreads();

    bfrag a[2], bfr[2];
#pragma unroll
    for (int mt = 0; mt < 2; mt++)
      a[mt] = *(const bfrag*)&Al[wm * 32 + mt * 16 + l16][quad * 8];
#pragma unroll
    for (int nt = 0; nt < 2; nt++)
      bfr[nt] = *(const bfrag*)&Bl[wn * 32 + nt * 16 + l16][quad * 8];
#pragma unroll
    for (int mt = 0; mt < 2; mt++)
#pragma unroll
      for (int nt = 0; nt < 2; nt++)
        acc[mt][nt] =
            __builtin_amdgcn_mfma_f32_16x16x32_bf16(a[mt], bfr[nt], acc[mt][nt], 0, 0, 0);
    __syncthreads();
  }

#pragma unroll
  for (int mt = 0; mt < 2; mt++)
#pragma unroll
    for (int nt = 0; nt < 2; nt++)
#pragma unroll
      for (int r = 0; r < 4; r++) {
        int e = e0 + wm * 32 + mt * 16 + quad * 4 + r;
        int d = d0 + wn * 32 + nt * 16 + l16;
        kv[(size_t)b * PROJ * EMBED + (size_t)e * EMBED + d] = f2bf(acc[mt][nt][r]);
      }
}

// ---------------------------------------------------------------------------
// Stage C: out[b][l][d] = (sum_e q'[b][l][e] * kv[b][e][d]) * zinv[b][l].
// Per batch M=4096(l), N=1024(d), K=256(e). Block 128x64, BK=32, waves 2x2.
// ---------------------------------------------------------------------------
__global__ __launch_bounds__(256) void out_kernel(
    const unsigned short* __restrict__ qp, const unsigned short* __restrict__ kv,
    const float* __restrict__ zinv, float* __restrict__ out) {
  __shared__ unsigned short Al[128][40];  // q' tile [l][e]
  __shared__ unsigned short Bl[64][40];   // kv transposed [d][e]
  __shared__ float zv[128];
  const int tid  = threadIdx.x;
  const int wave = tid >> 6, lane = tid & 63;
  const int quad = lane >> 4, l16 = lane & 15;
  const int wm = wave >> 1, wn = wave & 1;
  const int d0 = blockIdx.x * 64;
  const int l0 = blockIdx.y * 128;
  const int b  = blockIdx.z;
  const unsigned short* qpb = qp + (size_t)b * LSEQ * PROJ;
  const unsigned short* kvb = kv + (size_t)b * PROJ * EMBED;

  if (tid < 128) zv[tid] = zinv[b * LSEQ + l0 + tid];

  f4 acc[4][2];
#pragma unroll
  for (int i = 0; i < 4; i++)
#pragma unroll
    for (int j = 0; j < 2; j++) acc[i][j] = (f4){0.f, 0.f, 0.f, 0.f};

  const int bn = tid & 63, bk = tid >> 6;

  for (int k0 = 0; k0 < PROJ; k0 += 32) {
#pragma unroll
    for (int it = 0; it < 2; it++) {
      int slot = it * 256 + tid;
      int row = slot >> 2, ch = slot & 3;
      *(u16x8*)&Al[row][ch * 8] =
          *(const u16x8*)(qpb + (size_t)(l0 + row) * PROJ + k0 + ch * 8);
    }
    u16x8 h;
#pragma unroll
    for (int i = 0; i < 8; i++)
      h[i] = kvb[(size_t)(k0 + bk * 8 + i) * EMBED + d0 + bn];
    *(u16x8*)&Bl[bn][bk * 8] = h;
    __syncthreads();

    bfrag a[4], bfr[2];
#pragma unroll
    for (int mt = 0; mt < 4; mt++)
      a[mt] = *(const bfrag*)&Al[wm * 64 + mt * 16 + l16][quad * 8];
#pragma unroll
    for (int nt = 0; nt < 2; nt++)
      bfr[nt] = *(const bfrag*)&Bl[wn * 32 + nt * 16 + l16][quad * 8];
#pragma unroll
    for (int mt = 0; mt < 4; mt++)
#pragma unroll
      for (int nt = 0; nt < 2; nt++)
        acc[mt][nt] =
            __builtin_amdgcn_mfma_f32_16x16x32_bf16(a[mt], bfr[nt], acc[mt][nt], 0, 0, 0);
    __syncthreads();
  }

#pragma unroll
  for (int mt = 0; mt < 4; mt++)
#pragma unroll
    for (int nt = 0; nt < 2; nt++)
#pragma unroll
      for (int r = 0; r < 4; r++) {
        int rl = wm * 64 + mt * 16 + quad * 4 + r;
        int d  = d0 + wn * 32 + nt * 16 + l16;
        out[(size_t)b * LSEQ * EMBED + (size_t)(l0 + rl) * EMBED + d] =
            acc[mt][nt][r] * zv[rl];
      }
}

// ---------------------------------------------------------------------------
// Workspace layout (bytes):
//   qp   @ 0         : 32768*256*2  = 16,777,216   (q' bf16, [m][e])
//   kT   @ 16777216  : 8*256*4096*2 = 16,777,216   (k' bf16 transposed [b][e][l])
//   kv   @ 33554432  : 8*256*1024*2 =  4,194,304   (kv bf16 [b][e][d])
//   zinv @ 37748736  : 32768*4      =    131,072
// total ~37.9 MB
// ---------------------------------------------------------------------------
extern "C" void kernel_launch(void* const* d_in, const int* in_sizes, int n_in,
                              void* d_out, int out_size, void* d_ws, size_t ws_size,
                              hipStream_t stream) {
  const float* x  = (const float*)d_in[0];
  const float* qw = (const float*)d_in[1];
  const float* kw = (const float*)d_in[2];
  float* out = (float*)d_out;

  char* ws = (char*)d_ws;
  unsigned short* qp   = (unsigned short*)(ws);
  unsigned short* kT   = (unsigned short*)(ws + 16777216);
  unsigned short* kv   = (unsigned short*)(ws + 33554432);
  float*          zinv = (float*)(ws + 37748736);

  proj_exp_kernel<<<dim3(8, 256), 256, 0, stream>>>(x, qw, kw, qp, kT);
  zinv_kernel<<<dim3(8192), 256, 0, stream>>>(qp, zinv);
  kv_kernel<<<dim3(16, 4, 8), 256, 0, stream>>>(kT, x, kv);
  out_kernel<<<dim3(16, 32, 8), 256, 0, stream>>>(qp, kv, zinv, out);
}

// Round 2
// 396.257 us; speedup vs baseline: 1.3278x; 1.3278x over previous
//
#include <hip/hip_runtime.h>

// ---------------------------------------------------------------------------
// LinearAttention (FAVOR-style), all GEMMs as bf16 MFMA 16x16x32, m97-style:
//   cvtx:  x fp32 -> xb[b][l][d] bf16  AND  xT[b][d][l] bf16 (one read of x)
//   cvtw:  qw,kw fp32 -> wt[n][k] bf16 (n in [0,512): q cols then k cols)
//   proj:  C = x @ W (128x128 tile, BK=64, global_load_lds + XOR-swizzled LDS)
//          q-half -> exp -> qp[m][e]; k-half -> exp -> kT[b][e][l] (transposed)
//   zinv:  1/(rowsum(qp)+1e-8)
//   kv:    kT @ x  (K-split 8, fp32 partials)  -> kvreduce -> kvT[b][d][e]
//   out:   (qp @ kv) * zinv
// ---------------------------------------------------------------------------

#define EMBED 1024
#define PROJ  256
#define LSEQ  4096
#define BATCH 8

typedef short  bfrag __attribute__((ext_vector_type(8)));  // 8 bf16 = 1 MFMA frag
typedef float  f4    __attribute__((ext_vector_type(4)));
typedef unsigned short u16x8 __attribute__((ext_vector_type(8)));
typedef unsigned short u16x4 __attribute__((ext_vector_type(4)));

static __device__ __forceinline__ unsigned short f2bf(float f) {
  unsigned int u = __builtin_bit_cast(unsigned int, f);
  u += 0x7fffu + ((u >> 16) & 1u);  // RNE
  return (unsigned short)(u >> 16);
}
static __device__ __forceinline__ float bf2f(unsigned short h) {
  unsigned int u = ((unsigned int)h) << 16;
  return __builtin_bit_cast(float, u);
}

// async global->LDS, 16 B per lane; LDS dest = wave-uniform base + lane*16
static __device__ __forceinline__ void gload_lds16(const void* g, void* l) {
  __builtin_amdgcn_global_load_lds(
      (__attribute__((address_space(1))) void*)(unsigned long long)(g),
      (__attribute__((address_space(3))) void*)(unsigned)(unsigned long long)(l),
      16, 0, 0);
}

// Stage a 128x64 bf16 tile. LDS layout: row-major rows of 8 16B-chunks,
// chunk stored at position p = c ^ (r&7)  (XOR swizzle: conflict-free b128
// frag reads, and LDS dest stays lane-sequential for global_load_lds).
static __device__ __forceinline__ void stage_tile(
    const unsigned short* __restrict__ src, int row0, int stride, int k0,
    unsigned short* lds, int wave, int lane) {
#pragma unroll
  for (int j = 0; j < 4; j++) {
    int slot = (wave * 4 + j) * 64 + lane;
    int r = slot >> 3, cp = slot & 7;
    int c = cp ^ (r & 7);
    gload_lds16(src + (size_t)(row0 + r) * stride + k0 + c * 8,
                lds + (wave * 4 + j) * 512);
  }
}

// read one 16B MFMA fragment from the swizzled tile
static __device__ __forceinline__ bfrag read_frag(const unsigned short* lds,
                                                  int row, int chunk) {
  return *(const bfrag*)(lds + ((row << 3) + (chunk ^ (row & 7))) * 8);
}

// ---------------------------------------------------------------------------
// cvtx: x fp32 [b][l][d] -> xb bf16 [b][l][d] + xT bf16 [b][d][l]
// ---------------------------------------------------------------------------
__global__ __launch_bounds__(256) void cvtx_kernel(
    const float* __restrict__ x, unsigned short* __restrict__ xb,
    unsigned short* __restrict__ xT) {
  __shared__ unsigned short T[64][72];
  const int tid = threadIdx.x;
  const int d0 = blockIdx.x * 64, l0 = blockIdx.y * 64, b = blockIdx.z;
#pragma unroll
  for (int it = 0; it < 4; it++) {
    int slot = it * 256 + tid;
    int r = slot >> 4, c4 = slot & 15;
    f4 v = *(const f4*)(x + ((size_t)(b * LSEQ + l0 + r)) * EMBED + d0 + c4 * 4);
    u16x4 h = (u16x4){f2bf(v[0]), f2bf(v[1]), f2bf(v[2]), f2bf(v[3])};
    *(u16x4*)(xb + ((size_t)(b * LSEQ + l0 + r)) * EMBED + d0 + c4 * 4) = h;
    T[c4 * 4 + 0][r] = h[0];
    T[c4 * 4 + 1][r] = h[1];
    T[c4 * 4 + 2][r] = h[2];
    T[c4 * 4 + 3][r] = h[3];
  }
  __syncthreads();
#pragma unroll
  for (int it = 0; it < 2; it++) {
    int slot = it * 256 + tid;
    int d = slot >> 3, ch = slot & 7;
    *(u16x8*)(xT + ((size_t)(b * EMBED + d0 + d)) * LSEQ + l0 + ch * 8) =
        *(const u16x8*)&T[d][ch * 8];
  }
}

// ---------------------------------------------------------------------------
// cvtw: qw/kw fp32 [k][n] -> wt bf16 [n][k], n in [0,512) = [q | k]
// ---------------------------------------------------------------------------
__global__ __launch_bounds__(256) void cvtw_kernel(
    const float* __restrict__ qw, const float* __restrict__ kw,
    unsigned short* __restrict__ wt) {
  __shared__ unsigned short T[64][72];
  const int tid = threadIdx.x;
  const int n0 = blockIdx.x * 64, k0 = blockIdx.y * 64;
  const float* W = blockIdx.z ? kw : qw;
#pragma unroll
  for (int it = 0; it < 4; it++) {
    int slot = it * 256 + tid;
    int r = slot >> 4, c4 = slot & 15;  // r: k-local, c4: n-chunk
    f4 v = *(const f4*)(W + (size_t)(k0 + r) * PROJ + n0 + c4 * 4);
#pragma unroll
    for (int j = 0; j < 4; j++) T[c4 * 4 + j][r] = f2bf(v[j]);
  }
  __syncthreads();
#pragma unroll
  for (int it = 0; it < 2; it++) {
    int slot = it * 256 + tid;
    int n = slot >> 3, ch = slot & 7;
    *(u16x8*)(wt + ((size_t)(blockIdx.z * PROJ + n0 + n)) * EMBED + k0 + ch * 8) =
        *(const u16x8*)&T[n][ch * 8];
  }
}

// ---------------------------------------------------------------------------
// proj: C[m][n] = exp(xb @ wt^T). M=32768, N=512, K=1024. 128x128 tile, BK=64.
// ---------------------------------------------------------------------------
__global__ __launch_bounds__(256) void proj_kernel(
    const unsigned short* __restrict__ xb, const unsigned short* __restrict__ wt,
    unsigned short* __restrict__ qp, unsigned short* __restrict__ kT) {
  __shared__ union {
    struct { unsigned short A[128 * 64]; unsigned short B[128 * 64]; } t;
    unsigned short T[128 * 136];
  } sm;
  const int tid = threadIdx.x, wave = tid >> 6, lane = tid & 63;
  const int quad = lane >> 4, l16 = lane & 15;
  const int wm = wave >> 1, wn = wave & 1;
  const int n0 = blockIdx.x * 128, m0 = blockIdx.y * 128;

  f4 acc[4][4];
#pragma unroll
  for (int i = 0; i < 4; i++)
#pragma unroll
    for (int j = 0; j < 4; j++) acc[i][j] = (f4){0.f, 0.f, 0.f, 0.f};

  for (int k0 = 0; k0 < EMBED; k0 += 64) {
    stage_tile(xb, m0, EMBED, k0, sm.t.A, wave, lane);
    stage_tile(wt, n0, EMBED, k0, sm.t.B, wave, lane);
    __syncthreads();
#pragma unroll
    for (int ks = 0; ks < 2; ks++) {
      bfrag a[4], bfr[4];
#pragma unroll
      for (int mt = 0; mt < 4; mt++)
        a[mt] = read_frag(sm.t.A, wm * 64 + mt * 16 + l16, ks * 4 + quad);
#pragma unroll
      for (int nt = 0; nt < 4; nt++)
        bfr[nt] = read_frag(sm.t.B, wn * 64 + nt * 16 + l16, ks * 4 + quad);
#pragma unroll
      for (int mt = 0; mt < 4; mt++)
#pragma unroll
        for (int nt = 0; nt < 4; nt++)
          acc[mt][nt] = __builtin_amdgcn_mfma_f32_16x16x32_bf16(
              a[mt], bfr[nt], acc[mt][nt], 0, 0, 0);
    }
    __syncthreads();
  }

  if (n0 < PROJ) {
    // q-half: T[l][e], then coalesced rows into qp[m][e]
#pragma unroll
    for (int mt = 0; mt < 4; mt++)
#pragma unroll
      for (int nt = 0; nt < 4; nt++)
#pragma unroll
        for (int r = 0; r < 4; r++)
          sm.T[(wm * 64 + mt * 16 + quad * 4 + r) * 136 + wn * 64 + nt * 16 + l16] =
              f2bf(__expf(acc[mt][nt][r]));
    __syncthreads();
#pragma unroll
    for (int it = 0; it < 8; it++) {
      int slot = it * 256 + tid;
      int row = slot >> 4, ch = slot & 15;
      *(u16x8*)(qp + (size_t)(m0 + row) * PROJ + n0 + ch * 8) =
          *(const u16x8*)&sm.T[row * 136 + ch * 8];
    }
  } else {
    // k-half: T[e][l], then coalesced rows into kT[b][e][l]
#pragma unroll
    for (int mt = 0; mt < 4; mt++)
#pragma unroll
      for (int nt = 0; nt < 4; nt++) {
        u16x4 h;
#pragma unroll
        for (int r = 0; r < 4; r++) h[r] = f2bf(__expf(acc[mt][nt][r]));
        *(u16x4*)&sm.T[(wn * 64 + nt * 16 + l16) * 136 + wm * 64 + mt * 16 + quad * 4] = h;
      }
    __syncthreads();
    const int bb = m0 >> 12, l0 = m0 & 4095, ebase = n0 - PROJ;
#pragma unroll
    for (int it = 0; it < 8; it++) {
      int slot = it * 256 + tid;
      int e = slot >> 4, ch = slot & 15;
      *(u16x8*)(kT + (size_t)(bb * PROJ + ebase + e) * LSEQ + l0 + ch * 8) =
          *(const u16x8*)&sm.T[e * 136 + ch * 8];
    }
  }
}

// ---------------------------------------------------------------------------
// zinv[m] = 1 / (sum_e qp[m][e] + 1e-8)
// ---------------------------------------------------------------------------
__global__ __launch_bounds__(256) void zinv_kernel(
    const unsigned short* __restrict__ qp, float* __restrict__ zinv) {
  int m = blockIdx.x * 4 + (threadIdx.x >> 6);
  int lane = threadIdx.x & 63;
  u16x4 h = *(const u16x4*)(qp + (size_t)m * PROJ + lane * 4);
  float s = bf2f(h[0]) + bf2f(h[1]) + bf2f(h[2]) + bf2f(h[3]);
#pragma unroll
  for (int off = 32; off; off >>= 1) s += __shfl_xor(s, off);
  if (lane == 0) zinv[m] = 1.0f / (s + 1e-8f);
}

// ---------------------------------------------------------------------------
// kv: kvp[split][b][e][d] = sum_{l in chunk} kT[b][e][l] * xT[b][d][l]
// 128x128 tile, BK=64, K-chunk=512 (split 8).
// ---------------------------------------------------------------------------
__global__ __launch_bounds__(256) void kv_kernel(
    const unsigned short* __restrict__ kT, const unsigned short* __restrict__ xT,
    float* __restrict__ kvp) {
  __shared__ struct { unsigned short A[128 * 64]; unsigned short B[128 * 64]; } sm;
  const int tid = threadIdx.x, wave = tid >> 6, lane = tid & 63;
  const int quad = lane >> 4, l16 = lane & 15;
  const int wm = wave >> 1, wn = wave & 1;
  const int d0 = blockIdx.x * 128, e0 = blockIdx.y * 128;
  const int b = blockIdx.z & 7, split = blockIdx.z >> 3;
  const unsigned short* As = kT + (size_t)b * PROJ * LSEQ;
  const unsigned short* Bs = xT + (size_t)b * EMBED * LSEQ;

  f4 acc[4][4];
#pragma unroll
  for (int i = 0; i < 4; i++)
#pragma unroll
    for (int j = 0; j < 4; j++) acc[i][j] = (f4){0.f, 0.f, 0.f, 0.f};

  const int kbase = split * 512;
  for (int kk = 0; kk < 512; kk += 64) {
    stage_tile(As, e0, LSEQ, kbase + kk, sm.A, wave, lane);
    stage_tile(Bs, d0, LSEQ, kbase + kk, sm.B, wave, lane);
    __syncthreads();
#pragma unroll
    for (int ks = 0; ks < 2; ks++) {
      bfrag a[4], bfr[4];
#pragma unroll
      for (int mt = 0; mt < 4; mt++)
        a[mt] = read_frag(sm.A, wm * 64 + mt * 16 + l16, ks * 4 + quad);
#pragma unroll
      for (int nt = 0; nt < 4; nt++)
        bfr[nt] = read_frag(sm.B, wn * 64 + nt * 16 + l16, ks * 4 + quad);
#pragma unroll
      for (int mt = 0; mt < 4; mt++)
#pragma unroll
        for (int nt = 0; nt < 4; nt++)
          acc[mt][nt] = __builtin_amdgcn_mfma_f32_16x16x32_bf16(
              a[mt], bfr[nt], acc[mt][nt], 0, 0, 0);
    }
    __syncthreads();
  }

#pragma unroll
  for (int mt = 0; mt < 4; mt++)
#pragma unroll
    for (int nt = 0; nt < 4; nt++)
#pragma unroll
      for (int r = 0; r < 4; r++) {
        int e = e0 + wm * 64 + mt * 16 + quad * 4 + r;
        int d = d0 + wn * 64 + nt * 16 + l16;
        kvp[((size_t)(split * 8 + b) * PROJ + e) * EMBED + d] = acc[mt][nt][r];
      }
}

// ---------------------------------------------------------------------------
// kvreduce: kvT[b][d][e] bf16 = f2bf( sum_split kvp[split][b][e][d] )
// ---------------------------------------------------------------------------
__global__ __launch_bounds__(256) void kvreduce_kernel(
    const float* __restrict__ kvp, unsigned short* __restrict__ kvT) {
  __shared__ float T[64][68];
  const int tid = threadIdx.x;
  const int d0 = blockIdx.x * 64, e0 = blockIdx.y * 64, b = blockIdx.z;
#pragma unroll
  for (int it = 0; it < 4; it++) {
    int slot = it * 256 + tid;
    int e = slot >> 4, c4 = slot & 15;
    f4 s = (f4){0.f, 0.f, 0.f, 0.f};
#pragma unroll
    for (int sp = 0; sp < 8; sp++)
      s += *(const f4*)(kvp + ((size_t)(sp * 8 + b) * PROJ + e0 + e) * EMBED + d0 + c4 * 4);
#pragma unroll
    for (int j = 0; j < 4; j++) T[c4 * 4 + j][e] = s[j];
  }
  __syncthreads();
#pragma unroll
  for (int it = 0; it < 2; it++) {
    int slot = it * 256 + tid;
    int d = slot >> 3, ch = slot & 7;
    u16x8 h;
#pragma unroll
    for (int j = 0; j < 8; j++) h[j] = f2bf(T[d][ch * 8 + j]);
    *(u16x8*)(kvT + ((size_t)(b * EMBED + d0 + d)) * PROJ + e0 + ch * 8) = h;
  }
}

// ---------------------------------------------------------------------------
// out: out[b][l][d] = (qp[b][l][:] @ kv[b][:][d]) * zinv[b][l]
// A = qp [l][e], B = kvT [d][e]. 128x128 tile, BK=64, K=256.
// ---------------------------------------------------------------------------
__global__ __launch_bounds__(256) void out_kernel(
    const unsigned short* __restrict__ qp, const unsigned short* __restrict__ kvT,
    const float* __restrict__ zinv, float* __restrict__ out) {
  __shared__ struct { unsigned short A[128 * 64]; unsigned short B[128 * 64]; } sm;
  __shared__ float zv[128];
  const int tid = threadIdx.x, wave = tid >> 6, lane = tid & 63;
  const int quad = lane >> 4, l16 = lane & 15;
  const int wm = wave >> 1, wn = wave & 1;
  const int d0 = blockIdx.x * 128, l0 = blockIdx.y * 128, b = blockIdx.z;
  const unsigned short* As = qp + (size_t)b * LSEQ * PROJ;
  const unsigned short* Bs = kvT + (size_t)b * EMBED * PROJ;

  if (tid < 128) zv[tid] = zinv[b * LSEQ + l0 + tid];

  f4 acc[4][4];
#pragma unroll
  for (int i = 0; i < 4; i++)
#pragma unroll
    for (int j = 0; j < 4; j++) acc[i][j] = (f4){0.f, 0.f, 0.f, 0.f};

  for (int k0 = 0; k0 < PROJ; k0 += 64) {
    stage_tile(As, l0, PROJ, k0, sm.A, wave, lane);
    stage_tile(Bs, d0, PROJ, k0, sm.B, wave, lane);
    __syncthreads();
#pragma unroll
    for (int ks = 0; ks < 2; ks++) {
      bfrag a[4], bfr[4];
#pragma unroll
      for (int mt = 0; mt < 4; mt++)
        a[mt] = read_frag(sm.A, wm * 64 + mt * 16 + l16, ks * 4 + quad);
#pragma unroll
      for (int nt = 0; nt < 4; nt++)
        bfr[nt] = read_frag(sm.B, wn * 64 + nt * 16 + l16, ks * 4 + quad);
#pragma unroll
      for (int mt = 0; mt < 4; mt++)
#pragma unroll
        for (int nt = 0; nt < 4; nt++)
          acc[mt][nt] = __builtin_amdgcn_mfma_f32_16x16x32_bf16(
              a[mt], bfr[nt], acc[mt][nt], 0, 0, 0);
    }
    __syncthreads();
  }

#pragma unroll
  for (int mt = 0; mt < 4; mt++)
#pragma unroll
    for (int nt = 0; nt < 4; nt++)
#pragma unroll
      for (int r = 0; r < 4; r++) {
        int row = wm * 64 + mt * 16 + quad * 4 + r;
        int d = d0 + wn * 64 + nt * 16 + l16;
        out[((size_t)(b * LSEQ + l0 + row)) * EMBED + d] = acc[mt][nt][r] * zv[row];
      }
}

// ---------------------------------------------------------------------------
// Workspace layout (bytes):
//   xb   @ 0          67,108,864   (bf16 [b][l][d]) -- aliased by kvp later
//   xT   @ 67108864   67,108,864   (bf16 [b][d][l])
//   wt   @ 134217728   1,048,576   (bf16 [n][k], n=[q|k])
//   qp   @ 135266304  16,777,216   (bf16 [m][e])
//   kT   @ 152043520  16,777,216   (bf16 [b][e][l])
//   kvT  @ 168820736   4,194,304   (bf16 [b][d][e])
//   zinv @ 173015040     131,072
//   kvp = xb region (67,108,864 = 8 splits * 8 * 256 * 1024 * 4)  [xb dead]
// total ~165 MB
// ---------------------------------------------------------------------------
extern "C" void kernel_launch(void* const* d_in, const int* in_sizes, int n_in,
                              void* d_out, int out_size, void* d_ws, size_t ws_size,
                              hipStream_t stream) {
  const float* x  = (const float*)d_in[0];
  const float* qw = (const float*)d_in[1];
  const float* kw = (const float*)d_in[2];
  float* out = (float*)d_out;

  char* ws = (char*)d_ws;
  unsigned short* xb   = (unsigned short*)(ws);
  unsigned short* xT   = (unsigned short*)(ws + 67108864);
  unsigned short* wt   = (unsigned short*)(ws + 134217728);
  unsigned short* qp   = (unsigned short*)(ws + 135266304);
  unsigned short* kT   = (unsigned short*)(ws + 152043520);
  unsigned short* kvT  = (unsigned short*)(ws + 168820736);
  float*          zinv = (float*)(ws + 173015040);
  float*          kvp  = (float*)(ws);  // aliases xb (dead after proj)

  cvtx_kernel<<<dim3(16, 64, 8), 256, 0, stream>>>(x, xb, xT);
  cvtw_kernel<<<dim3(4, 16, 2), 256, 0, stream>>>(qw, kw, wt);
  proj_kernel<<<dim3(4, 256), 256, 0, stream>>>(xb, wt, qp, kT);
  zinv_kernel<<<dim3(8192), 256, 0, stream>>>(qp, zinv);
  kv_kernel<<<dim3(8, 2, 64), 256, 0, stream>>>(kT, xT, kvp);
  kvreduce_kernel<<<dim3(16, 4, 8), 256, 0, stream>>>(kvp, kvT);
  out_kernel<<<dim3(8, 32, 8), 256, 0, stream>>>(qp, kvT, zinv, out);
}